// Round 2
// baseline (333.748 us; speedup 1.0000x reference)
//
#include <hip/hip_runtime.h>

#define EMBED 768
#define POOL  32
#define PLEN  32
#define TOPK  5
#define NCLS  1000
#define SUF   12

// prompts row = 77*768 = 59136 floats = 14784 float4
//   prefix:   192 f4   [0,192)
//   combined: 6144 f4  [192,6336)
//   ctx:      6144 f4  [6336,12480)
//   suffix:   2304 f4  [12480,14784)
#define ROW_F4    14784
#define PRE_F4    192
#define COMB_END  6336
#define CTX_END   12480

// ---------------- kernel 1: top-5 selection ----------------
__global__ __launch_bounds__(256) void topk_kernel(
    const float* __restrict__ x_embed,   // [16,768]
    const float* __restrict__ key,       // [32,768]
    int* __restrict__ idx_out)           // [5]
{
    __shared__ float qs[EMBED];
    __shared__ float sim[POOL];
    int t = threadIdx.x;

    // q = sum over 16 frames (mean scale is rank-irrelevant)
    for (int d = t; d < EMBED; d += 256) {
        float s = 0.f;
        #pragma unroll
        for (int f = 0; f < 16; ++f) s += x_embed[f * EMBED + d];
        qs[d] = s;
    }
    __syncthreads();

    // 8 lanes per pool entry: dot(key_p, q) and ||key_p||
    int p = t >> 3, j = t & 7;
    float dot = 0.f, nrm = 0.f;
    for (int d = j; d < EMBED; d += 8) {
        float kv = key[p * EMBED + d];
        dot += kv * qs[d];
        nrm += kv * kv;
    }
    #pragma unroll
    for (int off = 4; off >= 1; off >>= 1) {
        dot += __shfl_down(dot, off, 8);
        nrm += __shfl_down(nrm, off, 8);
    }
    if (j == 0) sim[p] = dot * rsqrtf(nrm);
    __syncthreads();

    if (t == 0) {
        unsigned used = 0;
        for (int k = 0; k < TOPK; ++k) {
            float best = -1e30f; int bi = 0;
            for (int q = 0; q < POOL; ++q) {
                if (used & (1u << q)) continue;
                if (sim[q] > best) { best = sim[q]; bi = q; }
            }
            used |= 1u << bi;
            idx_out[k] = bi;
        }
    }
}

// ---------------- kernel 2: gated sum -> combined [32,768] ----------------
__global__ __launch_bounds__(256) void combined_kernel(
    const float* __restrict__ pool,      // [32,32,768]
    const float* __restrict__ alpha_w,   // [768]
    const float* __restrict__ alpha_b,   // [1]
    const int* __restrict__ idx,         // [5]
    float* __restrict__ combined)        // [32,768]
{
    int l = blockIdx.x;   // token position 0..31
    int t = threadIdx.x;
    __shared__ float red[256];
    __shared__ float wsh[TOPK];

    #pragma unroll
    for (int k = 0; k < TOPK; ++k) {
        const float* row = pool + ((size_t)idx[k] * PLEN + l) * EMBED;
        float s = 0.f;
        for (int d = t; d < EMBED; d += 256) s += row[d] * alpha_w[d];
        red[t] = s;
        __syncthreads();
        for (int off = 128; off >= 1; off >>= 1) {
            if (t < off) red[t] += red[t + off];
            __syncthreads();
        }
        if (t == 0) wsh[k] = 1.f / (1.f + __expf(-(red[0] + alpha_b[0])));
        __syncthreads();
    }

    for (int d = t; d < EMBED; d += 256) {
        float s = 0.f;
        #pragma unroll
        for (int k = 0; k < TOPK; ++k)
            s += wsh[k] * pool[((size_t)idx[k] * PLEN + l) * EMBED + d];
        combined[l * EMBED + d] = s;
    }
}

// ---------------- kernel 3: broadcast-concat writer ----------------
__global__ __launch_bounds__(256) void write_kernel(
    const float4* __restrict__ prefix,    // [1000,192]
    const float4* __restrict__ suffix,    // [1000,2304]
    const float4* __restrict__ ctx,       // [6144]
    const float4* __restrict__ combined,  // [6144]
    float4* __restrict__ out)
{
    int r   = blockIdx.y;                       // class 0..999
    int pos = blockIdx.x * 256 + threadIdx.x;   // 0..14847
    if (pos >= ROW_F4) return;

    float4 v;
    if (pos < PRE_F4)        v = prefix[(size_t)r * PRE_F4 + pos];
    else if (pos < COMB_END) v = combined[pos - PRE_F4];
    else if (pos < CTX_END)  v = ctx[pos - COMB_END];
    else                     v = suffix[(size_t)r * 2304 + (pos - CTX_END)];

    out[(size_t)r * ROW_F4 + pos] = v;
}

extern "C" void kernel_launch(void* const* d_in, const int* in_sizes, int n_in,
                              void* d_out, int out_size, void* d_ws, size_t ws_size,
                              hipStream_t stream) {
    const float* x_embed  = (const float*)d_in[0];
    const float* pool     = (const float*)d_in[1];
    const float* key      = (const float*)d_in[2];
    const float* alpha_w  = (const float*)d_in[3];
    const float* alpha_b  = (const float*)d_in[4];
    const float* ctx      = (const float*)d_in[5];
    const float* prefix   = (const float*)d_in[6];
    const float* suffix   = (const float*)d_in[7];
    float* out = (float*)d_out;

    int*   idx_ws      = (int*)d_ws;
    float* combined_ws = (float*)((char*)d_ws + 256);   // 32*768 floats

    topk_kernel<<<1, 256, 0, stream>>>(x_embed, key, idx_ws);
    combined_kernel<<<PLEN, 256, 0, stream>>>(pool, alpha_w, alpha_b, idx_ws, combined_ws);

    dim3 grid(58, NCLS);
    write_kernel<<<grid, 256, 0, stream>>>(
        (const float4*)prefix, (const float4*)suffix,
        (const float4*)ctx, (const float4*)combined_ws,
        (float4*)out);

    // pass-through outputs: prompt_pool then prompt_key
    size_t prompts_n = (size_t)NCLS * 77 * EMBED;          // 59,136,000
    size_t pool_n    = (size_t)POOL * PLEN * EMBED;        // 786,432
    size_t key_n     = (size_t)POOL * EMBED;               // 24,576
    hipMemcpyAsync(out + prompts_n, pool, pool_n * sizeof(float),
                   hipMemcpyDeviceToDevice, stream);
    hipMemcpyAsync(out + prompts_n + pool_n, key, key_n * sizeof(float),
                   hipMemcpyDeviceToDevice, stream);
}

// Round 3
// 320.178 us; speedup vs baseline: 1.0424x; 1.0424x over previous
//
#include <hip/hip_runtime.h>

#define EMBED 768
#define POOL  32
#define PLEN  32
#define TOPK  5
#define NCLS  1000

// prompts row = 77*768 = 59136 floats = 14784 float4
//   prefix:   192 f4   [0,192)
//   combined: 6144 f4  [192,6336)
//   ctx:      6144 f4  [6336,12480)
//   suffix:   2304 f4  [12480,14784)
#define ROW_F4     14784
#define PRE_F4     192
#define COMB_END   6336
#define CTX_END    12480
#define SUF_F4     2304

#define PROMPTS_F4 14784000        // 1000 * ROW_F4
#define POOL_F4    196608          // 32*32*768/4
#define KEY_F4     6144            // 32*768/4
#define TOTAL_F4   (PROMPTS_F4 + POOL_F4 + KEY_F4)   // 14,986,752 = 58542*256

// ---------------- kernel 1: fused top-5 + gated sum -> combined [32,768] ---
// 32 blocks (one per token position); each block redundantly recomputes the
// top-5 selection (reads are tiny and L2-hot), avoiding a separate launch.
__global__ __launch_bounds__(256) void selgate_kernel(
    const float* __restrict__ x_embed,   // [16,768]
    const float* __restrict__ key,       // [32,768]
    const float* __restrict__ pool,      // [32,32,768]
    const float* __restrict__ alpha_w,   // [768]
    const float* __restrict__ alpha_b,   // [1]
    float* __restrict__ combined)        // [32,768]
{
    __shared__ float qs[EMBED];
    __shared__ float sim[POOL];
    __shared__ int   idx[TOPK];
    __shared__ float red[256];
    __shared__ float wsh[TOPK];

    int l = blockIdx.x;    // token position 0..31
    int t = threadIdx.x;

    // q = sum over 16 frames (mean scaling is rank-irrelevant for top-k)
    for (int d = t; d < EMBED; d += 256) {
        float s = 0.f;
        #pragma unroll
        for (int f = 0; f < 16; ++f) s += x_embed[f * EMBED + d];
        qs[d] = s;
    }
    __syncthreads();

    // 8 lanes per pool entry: dot(key_p, q) and ||key_p||
    {
        int p = t >> 3, j = t & 7;
        float dot = 0.f, nrm = 0.f;
        for (int d = j; d < EMBED; d += 8) {
            float kv = key[p * EMBED + d];
            dot += kv * qs[d];
            nrm += kv * kv;
        }
        #pragma unroll
        for (int off = 4; off >= 1; off >>= 1) {
            dot += __shfl_down(dot, off, 8);
            nrm += __shfl_down(nrm, off, 8);
        }
        if (j == 0) sim[p] = dot * rsqrtf(nrm);
    }
    __syncthreads();

    if (t == 0) {
        unsigned used = 0;
        for (int k = 0; k < TOPK; ++k) {
            float best = -1e30f; int bi = 0;
            for (int q = 0; q < POOL; ++q) {
                if (used & (1u << q)) continue;
                if (sim[q] > best) { best = sim[q]; bi = q; }
            }
            used |= 1u << bi;
            idx[k] = bi;
        }
    }
    __syncthreads();

    // per-token sigmoid gates
    #pragma unroll
    for (int k = 0; k < TOPK; ++k) {
        const float* row = pool + ((size_t)idx[k] * PLEN + l) * EMBED;
        float s = 0.f;
        for (int d = t; d < EMBED; d += 256) s += row[d] * alpha_w[d];
        red[t] = s;
        __syncthreads();
        for (int off = 128; off >= 1; off >>= 1) {
            if (t < off) red[t] += red[t + off];
            __syncthreads();
        }
        if (t == 0) wsh[k] = 1.f / (1.f + __expf(-(red[0] + alpha_b[0])));
        __syncthreads();
    }

    for (int d = t; d < EMBED; d += 256) {
        float s = 0.f;
        #pragma unroll
        for (int k = 0; k < TOPK; ++k)
            s += wsh[k] * pool[((size_t)idx[k] * PLEN + l) * EMBED + d];
        combined[l * EMBED + d] = s;
    }
}

// ---------------- kernel 2: broadcast-concat writer + pass-through ---------
__global__ __launch_bounds__(256) void write_kernel(
    const float4* __restrict__ prefix,    // [1000,192]
    const float4* __restrict__ suffix,    // [1000,2304]
    const float4* __restrict__ ctx,       // [6144]
    const float4* __restrict__ combined,  // [6144]
    const float4* __restrict__ pool4,     // [196608]
    const float4* __restrict__ key4,      // [6144]
    float4* __restrict__ out)
{
    unsigned gpos = blockIdx.x * 256u + threadIdx.x;    // < TOTAL_F4

    float4 v;
    if (gpos < PROMPTS_F4) {
        unsigned r   = gpos / ROW_F4;       // magic-mul div by const
        unsigned pos = gpos - r * ROW_F4;
        if (pos < PRE_F4)        v = prefix[(size_t)r * PRE_F4 + pos];
        else if (pos < COMB_END) v = combined[pos - PRE_F4];
        else if (pos < CTX_END)  v = ctx[pos - COMB_END];
        else                     v = suffix[(size_t)r * SUF_F4 + (pos - CTX_END)];
    } else {
        unsigned q = gpos - PROMPTS_F4;     // pass-through: pool then key
        v = (q < POOL_F4) ? pool4[q] : key4[q - POOL_F4];
    }
    out[gpos] = v;
}

extern "C" void kernel_launch(void* const* d_in, const int* in_sizes, int n_in,
                              void* d_out, int out_size, void* d_ws, size_t ws_size,
                              hipStream_t stream) {
    const float* x_embed  = (const float*)d_in[0];
    const float* pool     = (const float*)d_in[1];
    const float* key      = (const float*)d_in[2];
    const float* alpha_w  = (const float*)d_in[3];
    const float* alpha_b  = (const float*)d_in[4];
    const float* ctx      = (const float*)d_in[5];
    const float* prefix   = (const float*)d_in[6];
    const float* suffix   = (const float*)d_in[7];
    float* out = (float*)d_out;

    float* combined_ws = (float*)d_ws;   // 32*768 floats

    selgate_kernel<<<PLEN, 256, 0, stream>>>(x_embed, key, pool, alpha_w,
                                             alpha_b, combined_ws);

    write_kernel<<<TOTAL_F4 / 256, 256, 0, stream>>>(
        (const float4*)prefix, (const float4*)suffix,
        (const float4*)ctx, (const float4*)combined_ws,
        (const float4*)pool, (const float4*)key,
        (float4*)out);
}